// Round 1
// baseline (353.605 us; speedup 1.0000x reference)
//
#include <hip/hip_runtime.h>

// DistortionLoss: out = 0.01 * mean_rays( (1/3)*sum s_i w_i^2
//                       + 2*sum_i (w_i m_i * Wexcl_i - w_i * WMexcl_i) )
// B=262144 rays, N=128 samples, fp32. HBM-read-bound: 402.7 MB -> ~64us floor.

constexpr int N_SAMPLES = 128;
constexpr int MAIN_BLOCKS = 4096;
constexpr int MAIN_THREADS = 256;

__global__ __launch_bounds__(MAIN_THREADS)
void distloss_main(const float* __restrict__ w,
                   const float* __restrict__ m,
                   const float* __restrict__ s,
                   float* __restrict__ partials, int B)
{
    const int tid  = threadIdx.x;
    const int lane = tid & 63;
    const int sl   = lane & 31;   // lane within 32-lane segment (one ray)
    const int half = lane >> 5;   // which ray of the wave's pair
    const int waveInBlock  = tid >> 6;
    const int wavesPerBlock = MAIN_THREADS >> 6;
    const int globalWave = blockIdx.x * wavesPerBlock + waveInBlock;
    const int totalWaves = gridDim.x * wavesPerBlock;
    const int P = B >> 1;         // ray pairs (2 rays per wave)

    float acc = 0.0f;

    for (int p = globalWave; p < P; p += totalWaves) {
        const int ray = p * 2 + half;
        const size_t base = (size_t)ray * N_SAMPLES + (size_t)sl * 4;
        const float4 w4 = *reinterpret_cast<const float4*>(w + base);
        const float4 m4 = *reinterpret_cast<const float4*>(m + base);
        const float4 s4 = *reinterpret_cast<const float4*>(s + base);

        const float wm0 = w4.x * m4.x;
        const float wm1 = w4.y * m4.y;
        const float wm2 = w4.z * m4.z;
        const float wm3 = w4.w * m4.w;

        const float uni = s4.x * w4.x * w4.x + s4.y * w4.y * w4.y
                        + s4.z * w4.z * w4.z + s4.w * w4.w * w4.w;

        // in-lane exclusive prefixes over the 4 owned elements
        const float ew1  = w4.x, ew2  = ew1 + w4.y, ew3  = ew2 + w4.z;
        const float tw   = ew3 + w4.w;
        const float ewm1 = wm0,  ewm2 = ewm1 + wm1, ewm3 = ewm2 + wm2;
        const float twm  = ewm3 + wm3;

        // inclusive scan of lane totals across the 32-lane segment.
        // guard (sl >= off) keeps the two segments of the wave independent:
        // for lanes 32..63 with sl>=off, lane-off stays in [32,63].
        float iw = tw, iwm = twm;
        #pragma unroll
        for (int off = 1; off < 32; off <<= 1) {
            const float aw  = __shfl_up(iw,  (unsigned)off);
            const float awm = __shfl_up(iwm, (unsigned)off);
            if (sl >= off) { iw += aw; iwm += awm; }
        }
        const float xw  = iw  - tw;   // segment-exclusive prefix of w
        const float xwm = iwm - twm;  // segment-exclusive prefix of w*m

        float bi;
        bi  = wm0 *  xw         - w4.x *  xwm;
        bi += wm1 * (xw + ew1)  - w4.y * (xwm + ewm1);
        bi += wm2 * (xw + ew2)  - w4.z * (xwm + ewm2);
        bi += wm3 * (xw + ew3)  - w4.w * (xwm + ewm3);

        acc += (1.0f / 3.0f) * uni + 2.0f * bi;
    }

    // wave64 butterfly reduction
    #pragma unroll
    for (int off = 1; off < 64; off <<= 1) acc += __shfl_xor(acc, off);

    __shared__ float smem[MAIN_THREADS / 64];
    if (lane == 0) smem[waveInBlock] = acc;
    __syncthreads();
    if (tid == 0) {
        float t = 0.0f;
        #pragma unroll
        for (int i = 0; i < MAIN_THREADS / 64; ++i) t += smem[i];
        partials[blockIdx.x] = t;
    }
}

__global__ __launch_bounds__(256)
void distloss_reduce(const float* __restrict__ partials, int n,
                     float* __restrict__ out, float scale)
{
    const int tid = threadIdx.x;
    float acc = 0.0f;
    for (int i = tid; i < n; i += 256) acc += partials[i];
    #pragma unroll
    for (int off = 1; off < 64; off <<= 1) acc += __shfl_xor(acc, off);
    __shared__ float smem[4];
    if ((tid & 63) == 0) smem[tid >> 6] = acc;
    __syncthreads();
    if (tid == 0) {
        out[0] = (smem[0] + smem[1] + smem[2] + smem[3]) * scale;
    }
}

extern "C" void kernel_launch(void* const* d_in, const int* in_sizes, int n_in,
                              void* d_out, int out_size, void* d_ws, size_t ws_size,
                              hipStream_t stream) {
    const float* w = (const float*)d_in[0];
    const float* m = (const float*)d_in[1];
    const float* s = (const float*)d_in[2];
    float* out = (float*)d_out;
    float* partials = (float*)d_ws;   // MAIN_BLOCKS floats, each block overwrites its slot

    const int B = in_sizes[0] / N_SAMPLES;
    const float scale = 0.01f / (float)B;   // LOSS_WEIGHT / B

    distloss_main<<<MAIN_BLOCKS, MAIN_THREADS, 0, stream>>>(w, m, s, partials, B);
    distloss_reduce<<<1, 256, 0, stream>>>(partials, MAIN_BLOCKS, out, scale);
}

// Round 2
// 326.291 us; speedup vs baseline: 1.0837x; 1.0837x over previous
//
#include <hip/hip_runtime.h>

// DistortionLoss: out = 0.01 * mean_rays( (1/3)*sum s_i w_i^2
//                       + 2*sum_i (w_i m_i * Wexcl_i - w_i * WMexcl_i) )
// B=262144 rays, N=128 samples, fp32. HBM-read-bound: 402.7 MB -> ~64us floor.
//
// R2: 2x unroll (4 rays/wave/iter, 6 float4 loads issued before scans) +
// nontemporal loads. R1 was 131us (3.07 TB/s, ~49% peak): VGPR=24 showed no
// software pipelining — loads drained serially before each ~600cy scan chain.

constexpr int N_SAMPLES = 128;
constexpr int MAIN_BLOCKS = 4096;
constexpr int MAIN_THREADS = 256;

typedef float v4f __attribute__((ext_vector_type(4)));

__device__ __forceinline__ float ray_contrib(v4f w4, v4f m4, v4f s4, int sl) {
    const float wm0 = w4.x * m4.x;
    const float wm1 = w4.y * m4.y;
    const float wm2 = w4.z * m4.z;
    const float wm3 = w4.w * m4.w;

    const float uni = s4.x * w4.x * w4.x + s4.y * w4.y * w4.y
                    + s4.z * w4.z * w4.z + s4.w * w4.w * w4.w;

    // in-lane exclusive prefixes over the 4 owned elements
    const float ew1  = w4.x, ew2  = ew1 + w4.y, ew3  = ew2 + w4.z;
    const float tw   = ew3 + w4.w;
    const float ewm1 = wm0,  ewm2 = ewm1 + wm1, ewm3 = ewm2 + wm2;
    const float twm  = ewm3 + wm3;

    // inclusive scan of lane totals across the 32-lane segment.
    // guard (sl >= off) keeps the two 32-lane segments of the wave independent.
    float iw = tw, iwm = twm;
    #pragma unroll
    for (int off = 1; off < 32; off <<= 1) {
        const float aw  = __shfl_up(iw,  (unsigned)off);
        const float awm = __shfl_up(iwm, (unsigned)off);
        if (sl >= off) { iw += aw; iwm += awm; }
    }
    const float xw  = iw  - tw;   // segment-exclusive prefix of w
    const float xwm = iwm - twm;  // segment-exclusive prefix of w*m

    float bi;
    bi  = wm0 *  xw         - w4.x *  xwm;
    bi += wm1 * (xw + ew1)  - w4.y * (xwm + ewm1);
    bi += wm2 * (xw + ew2)  - w4.z * (xwm + ewm2);
    bi += wm3 * (xw + ew3)  - w4.w * (xwm + ewm3);

    return (1.0f / 3.0f) * uni + 2.0f * bi;
}

__global__ __launch_bounds__(MAIN_THREADS)
void distloss_main(const float* __restrict__ w,
                   const float* __restrict__ m,
                   const float* __restrict__ s,
                   float* __restrict__ partials, int B)
{
    const int tid  = threadIdx.x;
    const int lane = tid & 63;
    const int sl   = lane & 31;   // lane within 32-lane segment (one ray)
    const int half = lane >> 5;   // which ray of the wave's pair
    const int waveInBlock  = tid >> 6;
    const int wavesPerBlock = MAIN_THREADS >> 6;
    const int globalWave = blockIdx.x * wavesPerBlock + waveInBlock;
    const int totalWaves = gridDim.x * wavesPerBlock;
    const int P = B >> 1;         // ray pairs (2 rays per wave per sub-step)

    float acc = 0.0f;

    // 2x unroll: pairs (p0, p0+1) -> 4 consecutive rays, 6 loads in flight.
    for (int p0 = globalWave * 2; p0 < P; p0 += totalWaves * 2) {
        const int ray_a = p0 * 2 + half;          // pair p0
        const size_t base_a = (size_t)ray_a * N_SAMPLES + (size_t)sl * 4;
        const size_t base_b = base_a + 2 * N_SAMPLES;  // pair p0+1 (rays +2)

        const v4f wa = __builtin_nontemporal_load(reinterpret_cast<const v4f*>(w + base_a));
        const v4f wb = __builtin_nontemporal_load(reinterpret_cast<const v4f*>(w + base_b));
        const v4f ma = __builtin_nontemporal_load(reinterpret_cast<const v4f*>(m + base_a));
        const v4f mb = __builtin_nontemporal_load(reinterpret_cast<const v4f*>(m + base_b));
        const v4f sa = __builtin_nontemporal_load(reinterpret_cast<const v4f*>(s + base_a));
        const v4f sb = __builtin_nontemporal_load(reinterpret_cast<const v4f*>(s + base_b));

        const float ca = ray_contrib(wa, ma, sa, sl);
        const float cb = ray_contrib(wb, mb, sb, sl);
        acc += ca + cb;
    }

    // wave64 butterfly reduction
    #pragma unroll
    for (int off = 1; off < 64; off <<= 1) acc += __shfl_xor(acc, off);

    __shared__ float smem[MAIN_THREADS / 64];
    if (lane == 0) smem[waveInBlock] = acc;
    __syncthreads();
    if (tid == 0) {
        float t = 0.0f;
        #pragma unroll
        for (int i = 0; i < MAIN_THREADS / 64; ++i) t += smem[i];
        partials[blockIdx.x] = t;
    }
}

__global__ __launch_bounds__(256)
void distloss_reduce(const float* __restrict__ partials, int n,
                     float* __restrict__ out, float scale)
{
    const int tid = threadIdx.x;
    float acc = 0.0f;
    for (int i = tid; i < n; i += 256) acc += partials[i];
    #pragma unroll
    for (int off = 1; off < 64; off <<= 1) acc += __shfl_xor(acc, off);
    __shared__ float smem[4];
    if ((tid & 63) == 0) smem[tid >> 6] = acc;
    __syncthreads();
    if (tid == 0) {
        out[0] = (smem[0] + smem[1] + smem[2] + smem[3]) * scale;
    }
}

extern "C" void kernel_launch(void* const* d_in, const int* in_sizes, int n_in,
                              void* d_out, int out_size, void* d_ws, size_t ws_size,
                              hipStream_t stream) {
    const float* w = (const float*)d_in[0];
    const float* m = (const float*)d_in[1];
    const float* s = (const float*)d_in[2];
    float* out = (float*)d_out;
    float* partials = (float*)d_ws;   // MAIN_BLOCKS floats, each block overwrites its slot

    const int B = in_sizes[0] / N_SAMPLES;
    const float scale = 0.01f / (float)B;   // LOSS_WEIGHT / B

    distloss_main<<<MAIN_BLOCKS, MAIN_THREADS, 0, stream>>>(w, m, s, partials, B);
    distloss_reduce<<<1, 256, 0, stream>>>(partials, MAIN_BLOCKS, out, scale);
}

// Round 3
// 323.845 us; speedup vs baseline: 1.0919x; 1.0076x over previous
//
#include <hip/hip_runtime.h>

// DistortionLoss: out = 0.01 * mean_rays( (1/3)*sum s_i w_i^2
//                       + 2*sum_i (w_i m_i * Wexcl_i - w_i * WMexcl_i) )
// B=262144 rays, N=128 samples, fp32. HBM-read-bound: 402.7 MB -> ~60us floor
// (harness's own 512MB fills run at ~6.9 TB/s on this part).
//
// R2: 2x unroll + nontemporal loads -> main fell 131us -> <77us (out of top-5).
// R3: 4x unroll: 8 rays/wave/iter, 12 float4 loads (192B/lane) issued before
// the 4 independent scan chains -> 2x more MLP, ~2 iterations per wave.

constexpr int N_SAMPLES = 128;
constexpr int MAIN_BLOCKS = 4096;
constexpr int MAIN_THREADS = 256;

typedef float v4f __attribute__((ext_vector_type(4)));

__device__ __forceinline__ float ray_contrib(v4f w4, v4f m4, v4f s4, int sl) {
    const float wm0 = w4.x * m4.x;
    const float wm1 = w4.y * m4.y;
    const float wm2 = w4.z * m4.z;
    const float wm3 = w4.w * m4.w;

    const float uni = s4.x * w4.x * w4.x + s4.y * w4.y * w4.y
                    + s4.z * w4.z * w4.z + s4.w * w4.w * w4.w;

    // in-lane exclusive prefixes over the 4 owned elements
    const float ew1  = w4.x, ew2  = ew1 + w4.y, ew3  = ew2 + w4.z;
    const float tw   = ew3 + w4.w;
    const float ewm1 = wm0,  ewm2 = ewm1 + wm1, ewm3 = ewm2 + wm2;
    const float twm  = ewm3 + wm3;

    // inclusive scan of lane totals across the 32-lane segment.
    // guard (sl >= off) keeps the two 32-lane segments of the wave independent.
    float iw = tw, iwm = twm;
    #pragma unroll
    for (int off = 1; off < 32; off <<= 1) {
        const float aw  = __shfl_up(iw,  (unsigned)off);
        const float awm = __shfl_up(iwm, (unsigned)off);
        if (sl >= off) { iw += aw; iwm += awm; }
    }
    const float xw  = iw  - tw;   // segment-exclusive prefix of w
    const float xwm = iwm - twm;  // segment-exclusive prefix of w*m

    float bi;
    bi  = wm0 *  xw         - w4.x *  xwm;
    bi += wm1 * (xw + ew1)  - w4.y * (xwm + ewm1);
    bi += wm2 * (xw + ew2)  - w4.z * (xwm + ewm2);
    bi += wm3 * (xw + ew3)  - w4.w * (xwm + ewm3);

    return (1.0f / 3.0f) * uni + 2.0f * bi;
}

__global__ __launch_bounds__(MAIN_THREADS)
void distloss_main(const float* __restrict__ w,
                   const float* __restrict__ m,
                   const float* __restrict__ s,
                   float* __restrict__ partials, int B)
{
    const int tid  = threadIdx.x;
    const int lane = tid & 63;
    const int sl   = lane & 31;   // lane within 32-lane segment (one ray)
    const int half = lane >> 5;   // which ray of the wave's pair
    const int waveInBlock  = tid >> 6;
    const int wavesPerBlock = MAIN_THREADS >> 6;
    const int globalWave = blockIdx.x * wavesPerBlock + waveInBlock;
    const int totalWaves = gridDim.x * wavesPerBlock;
    const int P = B >> 1;         // ray pairs (2 rays per wave per sub-step)

    float acc = 0.0f;

    // 4x unroll: pairs (p0 .. p0+3) -> 8 consecutive rays, 12 loads in flight.
    for (int p0 = globalWave * 4; p0 + 3 < P; p0 += totalWaves * 4) {
        const int ray_a = p0 * 2 + half;
        const size_t ba = (size_t)ray_a * N_SAMPLES + (size_t)sl * 4;
        const size_t bb = ba + 2 * N_SAMPLES;
        const size_t bc = ba + 4 * N_SAMPLES;
        const size_t bd = ba + 6 * N_SAMPLES;

        const v4f wa = __builtin_nontemporal_load(reinterpret_cast<const v4f*>(w + ba));
        const v4f wb = __builtin_nontemporal_load(reinterpret_cast<const v4f*>(w + bb));
        const v4f wc = __builtin_nontemporal_load(reinterpret_cast<const v4f*>(w + bc));
        const v4f wd = __builtin_nontemporal_load(reinterpret_cast<const v4f*>(w + bd));
        const v4f ma = __builtin_nontemporal_load(reinterpret_cast<const v4f*>(m + ba));
        const v4f mb = __builtin_nontemporal_load(reinterpret_cast<const v4f*>(m + bb));
        const v4f mc = __builtin_nontemporal_load(reinterpret_cast<const v4f*>(m + bc));
        const v4f md = __builtin_nontemporal_load(reinterpret_cast<const v4f*>(m + bd));
        const v4f sa = __builtin_nontemporal_load(reinterpret_cast<const v4f*>(s + ba));
        const v4f sb = __builtin_nontemporal_load(reinterpret_cast<const v4f*>(s + bb));
        const v4f sc = __builtin_nontemporal_load(reinterpret_cast<const v4f*>(s + bc));
        const v4f sd = __builtin_nontemporal_load(reinterpret_cast<const v4f*>(s + bd));

        acc += ray_contrib(wa, ma, sa, sl);
        acc += ray_contrib(wb, mb, sb, sl);
        acc += ray_contrib(wc, mc, sc, sl);
        acc += ray_contrib(wd, md, sd, sl);
    }

    // wave64 butterfly reduction
    #pragma unroll
    for (int off = 1; off < 64; off <<= 1) acc += __shfl_xor(acc, off);

    __shared__ float smem[MAIN_THREADS / 64];
    if (lane == 0) smem[waveInBlock] = acc;
    __syncthreads();
    if (tid == 0) {
        float t = 0.0f;
        #pragma unroll
        for (int i = 0; i < MAIN_THREADS / 64; ++i) t += smem[i];
        partials[blockIdx.x] = t;
    }
}

__global__ __launch_bounds__(256)
void distloss_reduce(const float* __restrict__ partials, int n,
                     float* __restrict__ out, float scale)
{
    const int tid = threadIdx.x;
    float acc = 0.0f;
    for (int i = tid; i < n; i += 256) acc += partials[i];
    #pragma unroll
    for (int off = 1; off < 64; off <<= 1) acc += __shfl_xor(acc, off);
    __shared__ float smem[4];
    if ((tid & 63) == 0) smem[tid >> 6] = acc;
    __syncthreads();
    if (tid == 0) {
        out[0] = (smem[0] + smem[1] + smem[2] + smem[3]) * scale;
    }
}

extern "C" void kernel_launch(void* const* d_in, const int* in_sizes, int n_in,
                              void* d_out, int out_size, void* d_ws, size_t ws_size,
                              hipStream_t stream) {
    const float* w = (const float*)d_in[0];
    const float* m = (const float*)d_in[1];
    const float* s = (const float*)d_in[2];
    float* out = (float*)d_out;
    float* partials = (float*)d_ws;   // MAIN_BLOCKS floats, each block overwrites its slot

    const int B = in_sizes[0] / N_SAMPLES;
    const float scale = 0.01f / (float)B;   // LOSS_WEIGHT / B

    distloss_main<<<MAIN_BLOCKS, MAIN_THREADS, 0, stream>>>(w, m, s, partials, B);
    distloss_reduce<<<1, 256, 0, stream>>>(partials, MAIN_BLOCKS, out, scale);
}